// Round 1
// baseline (1289.272 us; speedup 1.0000x reference)
//
#include <hip/hip_runtime.h>
#include <hip/hip_bf16.h>

// ---------------------------------------------------------------------------
// GCNRegression: 4x (GEMM 128x128 + symmetric-norm aggregation + ReLU),
// then global mean pool (128 graphs) + FC(128->1).
// ---------------------------------------------------------------------------

// ---- degree histogram -----------------------------------------------------
__global__ void count_deg_kernel(const int* __restrict__ dst, int* __restrict__ deg, int E) {
    int e = blockIdx.x * blockDim.x + threadIdx.x;
    if (e < E) atomicAdd(&deg[dst[e]], 1);
}

// ---- dinv = 1/sqrt(deg+1) (fp64 for accuracy; trivial cost) ---------------
__global__ void dinv_kernel(const int* __restrict__ deg, float* __restrict__ dinv, int n) {
    int i = blockIdx.x * blockDim.x + threadIdx.x;
    if (i < n) dinv[i] = (float)(1.0 / sqrt((double)(deg[i] + 1)));
}

// ---- single-block exclusive scan -> row_ptr -------------------------------
__global__ void scan_kernel(const int* __restrict__ cnt, int* __restrict__ row_ptr, int n) {
    __shared__ int sums[1024];
    int t = threadIdx.x;
    int per = (n + 1023) >> 10;
    int s = t * per;
    int e = s + per; if (e > n) e = n; if (s > n) s = n;
    int acc = 0;
    for (int i = s; i < e; i++) acc += cnt[i];
    sums[t] = acc;
    __syncthreads();
    // Hillis-Steele inclusive scan
    for (int off = 1; off < 1024; off <<= 1) {
        int u = (t >= off) ? sums[t - off] : 0;
        __syncthreads();
        sums[t] += u;
        __syncthreads();
    }
    int excl = sums[t] - acc;
    int run = excl;
    for (int i = s; i < e; i++) { row_ptr[i] = run; run += cnt[i]; }
    if (t == 1023) row_ptr[n] = sums[1023];
}

// ---- CSR fill (order within a node is nondeterministic; fp32-sum safe) ----
__global__ void csr_fill_kernel(const int* __restrict__ src, const int* __restrict__ dst,
                                const int* __restrict__ row_ptr, int* __restrict__ fill,
                                const float* __restrict__ dinv,
                                int* __restrict__ csr_src, float* __restrict__ csr_coef, int E) {
    int e = blockIdx.x * blockDim.x + threadIdx.x;
    if (e >= E) return;
    int d = dst[e];
    int s = src[e];
    int pos = row_ptr[d] + atomicAdd(&fill[d], 1);
    csr_src[pos] = s;
    csr_coef[pos] = dinv[s] * dinv[d];
}

// ---- GEMM: C[n x 128] = A[n x 128] @ W[128 x 128] (fp32, W in LDS) --------
__global__ __launch_bounds__(256) void gemm_kernel(const float* __restrict__ A,
                                                   const float* __restrict__ W,
                                                   float* __restrict__ C, int n) {
    __shared__ float sW[128 * 128];
    int t = threadIdx.x;
    {
        const float4* Wv = (const float4*)W;
        float4* sWv = (float4*)sW;
        #pragma unroll
        for (int i = 0; i < 16; i++) sWv[t + 256 * i] = Wv[t + 256 * i];
    }
    __syncthreads();

    int row0 = blockIdx.x * 64;
    int cg = (t & 31) * 4;         // 4 consecutive columns
    int rg = (t >> 5) * 8;         // 8 rows
    int rbase = row0 + rg;

    float acc[8][4];
    #pragma unroll
    for (int r = 0; r < 8; r++)
        #pragma unroll
        for (int c = 0; c < 4; c++) acc[r][c] = 0.f;

    for (int k = 0; k < 128; k += 4) {
        float4 a[8];
        #pragma unroll
        for (int r = 0; r < 8; r++) {
            int rr = rbase + r;
            a[r] = (rr < n) ? *(const float4*)(A + (size_t)rr * 128 + k)
                            : make_float4(0.f, 0.f, 0.f, 0.f);
        }
        #pragma unroll
        for (int kk = 0; kk < 4; kk++) {
            float4 w = *(const float4*)(sW + (size_t)(k + kk) * 128 + cg);
            #pragma unroll
            for (int r = 0; r < 8; r++) {
                float av = (kk == 0) ? a[r].x : (kk == 1) ? a[r].y : (kk == 2) ? a[r].z : a[r].w;
                acc[r][0] += av * w.x;
                acc[r][1] += av * w.y;
                acc[r][2] += av * w.z;
                acc[r][3] += av * w.w;
            }
        }
    }
    #pragma unroll
    for (int r = 0; r < 8; r++) {
        int rr = rbase + r;
        if (rr < n)
            *(float4*)(C + (size_t)rr * 128 + cg) =
                make_float4(acc[r][0], acc[r][1], acc[r][2], acc[r][3]);
    }
}

// ---- Aggregation: out[i] = relu(sum_e tmp[src]*coef + tmp[i]*dinv^2 + b) --
// one wave per node; lane handles 2 channels (float2), edges broadcast via shfl
__global__ __launch_bounds__(256) void agg_kernel(const float* __restrict__ tmp,
                                                  const int* __restrict__ row_ptr,
                                                  const int* __restrict__ csr_src,
                                                  const float* __restrict__ csr_coef,
                                                  const float* __restrict__ dinv,
                                                  const float* __restrict__ bias,
                                                  float* __restrict__ out, int n) {
    int wave = blockIdx.x * (blockDim.x >> 6) + (threadIdx.x >> 6);
    int lane = threadIdx.x & 63;
    if (wave >= n) return;
    int i = wave;

    float di = dinv[i];
    float sc = di * di;
    const float2* trow = (const float2*)(tmp + (size_t)i * 128);
    float2 self = trow[lane];
    float accx = self.x * sc;
    float accy = self.y * sc;

    int beg = row_ptr[i], end = row_ptr[i + 1];
    for (int e0 = beg; e0 < end; e0 += 64) {
        int m = end - e0; if (m > 64) m = 64;
        int   s  = 0;
        float cf = 0.f;
        if (lane < m) { s = csr_src[e0 + lane]; cf = csr_coef[e0 + lane]; }
        for (int j = 0; j < m; j++) {
            int   sj = __shfl(s, j);
            float cj = __shfl(cf, j);
            float2 v = ((const float2*)(tmp + (size_t)sj * 128))[lane];
            accx += v.x * cj;
            accy += v.y * cj;
        }
    }
    float2 b = ((const float2*)bias)[lane];
    float2 o;
    o.x = fmaxf(accx + b.x, 0.f);
    o.y = fmaxf(accy + b.y, 0.f);
    ((float2*)(out + (size_t)i * 128))[lane] = o;
}

// ---- mean pool per graph + FC(128->1); fp64 accumulation ------------------
__global__ __launch_bounds__(128) void pool_fc_kernel(const float* __restrict__ h,
                                                      const int* __restrict__ batch,
                                                      const float* __restrict__ Wfc,
                                                      const float* __restrict__ bfc,
                                                      float* __restrict__ out, int n) {
    int g = blockIdx.x;
    int c = threadIdx.x;  // 128 threads = 128 channels

    // lower_bound(batch, g) and lower_bound(batch, g+1); batch sorted
    int lo = 0, hi = n;
    while (lo < hi) { int mid = (lo + hi) >> 1; if (batch[mid] < g) lo = mid + 1; else hi = mid; }
    int start = lo;
    lo = start; hi = n;
    while (lo < hi) { int mid = (lo + hi) >> 1; if (batch[mid] < g + 1) lo = mid + 1; else hi = mid; }
    int end = lo;

    double sum = 0.0;
    for (int r = start; r < end; r++) sum += (double)h[(size_t)r * 128 + c];
    int cnt = end - start;
    double mean = sum / (double)(cnt > 0 ? cnt : 1);
    double v = mean * (double)Wfc[c];

    __shared__ double red[128];
    red[c] = v;
    __syncthreads();
    for (int off = 64; off > 0; off >>= 1) {
        if (c < off) red[c] += red[c + off];
        __syncthreads();
    }
    if (c == 0) out[g] = (float)(red[0] + (double)bfc[0]);
}

// ---------------------------------------------------------------------------
extern "C" void kernel_launch(void* const* d_in, const int* in_sizes, int n_in,
                              void* d_out, int out_size, void* d_ws, size_t ws_size,
                              hipStream_t stream) {
    const float* x          = (const float*)d_in[0];
    const int*   edge_index = (const int*)d_in[1];
    const int*   batch      = (const int*)d_in[2];
    const float* W1  = (const float*)d_in[3];
    const float* b1  = (const float*)d_in[4];
    const float* W2  = (const float*)d_in[5];
    const float* b2  = (const float*)d_in[6];
    const float* Wfc = (const float*)d_in[7];
    const float* bfc = (const float*)d_in[8];
    float* out = (float*)d_out;

    const int N = in_sizes[2];       // 50000
    const int E = in_sizes[1] / 2;   // 1600000
    const int G = out_size;          // 128 graphs

    const int* e_src = edge_index;
    const int* e_dst = edge_index + E;

    // ---- workspace layout (256B aligned) ----
    char* p = (char*)d_ws;
    auto alloc = [&](size_t bytes) {
        void* r = (void*)p;
        p += (bytes + 255) & ~(size_t)255;
        return r;
    };
    float* h0       = (float*)alloc((size_t)N * 128 * 4);
    float* h1       = (float*)alloc((size_t)N * 128 * 4);
    int*   csr_src  = (int*)  alloc((size_t)E * 4);
    float* csr_coef = (float*)alloc((size_t)E * 4);
    int*   row_ptr  = (int*)  alloc((size_t)(N + 1) * 4);
    int*   deg_cnt  = (int*)  alloc((size_t)N * 4);
    int*   fill     = (int*)  alloc((size_t)N * 4);
    float* dinv     = (float*)alloc((size_t)N * 4);
    (void)ws_size; (void)n_in;

    // ---- build normalization + CSR ----
    hipMemsetAsync(deg_cnt, 0, (size_t)N * 4, stream);
    hipMemsetAsync(fill,    0, (size_t)N * 4, stream);

    int tb = 256;
    count_deg_kernel<<<(E + tb - 1) / tb, tb, 0, stream>>>(e_dst, deg_cnt, E);
    dinv_kernel<<<(N + tb - 1) / tb, tb, 0, stream>>>(deg_cnt, dinv, N);
    scan_kernel<<<1, 1024, 0, stream>>>(deg_cnt, row_ptr, N);
    csr_fill_kernel<<<(E + tb - 1) / tb, tb, 0, stream>>>(e_src, e_dst, row_ptr, fill,
                                                          dinv, csr_src, csr_coef, E);

    // ---- layers ----
    int gemm_blocks = (N + 63) / 64;
    int agg_blocks  = (N + 3) / 4;   // 4 waves (nodes) per 256-thread block

    // layer 1: x @ W1 -> h1; agg -> h0
    gemm_kernel<<<gemm_blocks, 256, 0, stream>>>(x, W1, h1, N);
    agg_kernel<<<agg_blocks, 256, 0, stream>>>(h1, row_ptr, csr_src, csr_coef, dinv, b1, h0, N);

    // layers 2..4: h0 @ W2 -> h1; agg -> h0
    for (int l = 0; l < 3; l++) {
        gemm_kernel<<<gemm_blocks, 256, 0, stream>>>(h0, W2, h1, N);
        agg_kernel<<<agg_blocks, 256, 0, stream>>>(h1, row_ptr, csr_src, csr_coef, dinv, b2, h0, N);
    }

    // ---- pool + fc ----
    pool_fc_kernel<<<G, 128, 0, stream>>>(h0, batch, Wfc, bfc, out, N);
}

// Round 2
// 1198.101 us; speedup vs baseline: 1.0761x; 1.0761x over previous
//
#include <hip/hip_runtime.h>
#include <hip/hip_bf16.h>

// ---------------------------------------------------------------------------
// GCNRegression: 4x (GEMM 128x128 + symmetric-norm aggregation + ReLU),
// then global mean pool (128 graphs) + FC(128->1).
//
// R1 notes:
//  - csr_fill was 135us with 147MB WRITE_SIZE (11.5x amplification from 8B
//    scattered stores across 8 non-coherent XCD L2s). Fix: drop csr_coef
//    (compute dinv[src] on the fly in agg; dst factor applied once at end),
//    and partition the fill by dst-range keyed on blockIdx%8 so each CSR
//    line is written from exactly one XCD -> full-line writebacks.
//  - agg: unroll edge loop x4 for 4 concurrent gathers per wave.
// ---------------------------------------------------------------------------

// ---- degree histogram (int4-vectorized edge reads) ------------------------
__global__ void count_deg_kernel(const int* __restrict__ dst, int* __restrict__ deg, int E) {
    int i = blockIdx.x * blockDim.x + threadIdx.x;
    int e = i * 4;
    if (e + 3 < E) {
        int4 d = *(const int4*)(dst + e);
        atomicAdd(&deg[d.x], 1);
        atomicAdd(&deg[d.y], 1);
        atomicAdd(&deg[d.z], 1);
        atomicAdd(&deg[d.w], 1);
    } else {
        for (; e < E; e++) atomicAdd(&deg[dst[e]], 1);
    }
}

// ---- dinv = 1/sqrt(deg+1) (fp64 for accuracy; trivial cost) ---------------
__global__ void dinv_kernel(const int* __restrict__ deg, float* __restrict__ dinv, int n) {
    int i = blockIdx.x * blockDim.x + threadIdx.x;
    if (i < n) dinv[i] = (float)(1.0 / sqrt((double)(deg[i] + 1)));
}

// ---- single-block exclusive scan -> row_ptr -------------------------------
__global__ void scan_kernel(const int* __restrict__ cnt, int* __restrict__ row_ptr, int n) {
    __shared__ int sums[1024];
    int t = threadIdx.x;
    int per = (n + 1023) >> 10;
    int s = t * per;
    int e = s + per; if (e > n) e = n; if (s > n) s = n;
    int acc = 0;
    for (int i = s; i < e; i++) acc += cnt[i];
    sums[t] = acc;
    __syncthreads();
    for (int off = 1; off < 1024; off <<= 1) {
        int u = (t >= off) ? sums[t - off] : 0;
        __syncthreads();
        sums[t] += u;
        __syncthreads();
    }
    int excl = sums[t] - acc;
    int run = excl;
    for (int i = s; i < e; i++) { row_ptr[i] = run; run += cnt[i]; }
    if (t == 1023) row_ptr[n] = sums[1023];
}

// ---- CSR fill, XCD-range-partitioned --------------------------------------
// blockIdx%8 selects a dst range; under round-robin dispatch all blocks of a
// group land on one XCD, so each csr_src cache line is written by one XCD
// only -> L2 write-combining -> ~full-line writebacks (6.4MB, not 147MB).
__global__ __launch_bounds__(256) void csr_fill_kernel(const int* __restrict__ src,
                                                       const int* __restrict__ dst,
                                                       const int* __restrict__ row_ptr,
                                                       int* __restrict__ fill,
                                                       int* __restrict__ csr_src,
                                                       int E, int N) {
    int g  = blockIdx.x & 7;           // range group (== XCD under round-robin)
    int gb = blockIdx.x >> 3;          // block index within group
    int group_blocks = gridDim.x >> 3;
    int R  = (N + 7) >> 3;
    int lo = g * R;
    int hi = lo + R; if (hi > N) hi = N;

    int tig    = gb * blockDim.x + threadIdx.x;       // thread in group
    int stride = group_blocks * blockDim.x;
    int nq = (E + 3) >> 2;

    for (int q = tig; q < nq; q += stride) {
        int e = q * 4;
        if (e + 3 < E) {
            int4 d = *(const int4*)(dst + e);
            if (d.x >= lo && d.x < hi) {
                int pos = row_ptr[d.x] + atomicAdd(&fill[d.x], 1);
                csr_src[pos] = src[e + 0];
            }
            if (d.y >= lo && d.y < hi) {
                int pos = row_ptr[d.y] + atomicAdd(&fill[d.y], 1);
                csr_src[pos] = src[e + 1];
            }
            if (d.z >= lo && d.z < hi) {
                int pos = row_ptr[d.z] + atomicAdd(&fill[d.z], 1);
                csr_src[pos] = src[e + 2];
            }
            if (d.w >= lo && d.w < hi) {
                int pos = row_ptr[d.w] + atomicAdd(&fill[d.w], 1);
                csr_src[pos] = src[e + 3];
            }
        } else {
            for (; e < E; e++) {
                int d = dst[e];
                if (d >= lo && d < hi) {
                    int pos = row_ptr[d] + atomicAdd(&fill[d], 1);
                    csr_src[pos] = src[e];
                }
            }
        }
    }
}

// ---- GEMM: C[n x 128] = A[n x 128] @ W[128 x 128] (fp32, W in LDS) --------
__global__ __launch_bounds__(256) void gemm_kernel(const float* __restrict__ A,
                                                   const float* __restrict__ W,
                                                   float* __restrict__ C, int n) {
    __shared__ float sW[128 * 128];
    int t = threadIdx.x;
    {
        const float4* Wv = (const float4*)W;
        float4* sWv = (float4*)sW;
        #pragma unroll
        for (int i = 0; i < 16; i++) sWv[t + 256 * i] = Wv[t + 256 * i];
    }
    __syncthreads();

    int row0 = blockIdx.x * 64;
    int cg = (t & 31) * 4;
    int rg = (t >> 5) * 8;
    int rbase = row0 + rg;

    float acc[8][4];
    #pragma unroll
    for (int r = 0; r < 8; r++)
        #pragma unroll
        for (int c = 0; c < 4; c++) acc[r][c] = 0.f;

    for (int k = 0; k < 128; k += 4) {
        float4 a[8];
        #pragma unroll
        for (int r = 0; r < 8; r++) {
            int rr = rbase + r;
            a[r] = (rr < n) ? *(const float4*)(A + (size_t)rr * 128 + k)
                            : make_float4(0.f, 0.f, 0.f, 0.f);
        }
        #pragma unroll
        for (int kk = 0; kk < 4; kk++) {
            float4 w = *(const float4*)(sW + (size_t)(k + kk) * 128 + cg);
            #pragma unroll
            for (int r = 0; r < 8; r++) {
                float av = (kk == 0) ? a[r].x : (kk == 1) ? a[r].y : (kk == 2) ? a[r].z : a[r].w;
                acc[r][0] += av * w.x;
                acc[r][1] += av * w.y;
                acc[r][2] += av * w.z;
                acc[r][3] += av * w.w;
            }
        }
    }
    #pragma unroll
    for (int r = 0; r < 8; r++) {
        int rr = rbase + r;
        if (rr < n)
            *(float4*)(C + (size_t)rr * 128 + cg) =
                make_float4(acc[r][0], acc[r][1], acc[r][2], acc[r][3]);
    }
}

// ---- Aggregation ----------------------------------------------------------
// out[i] = relu( di * ( h[i]*di + sum_e dinv[src_e]*h[src_e] ) + b )
// one wave per node; lane = 2 channels (float2); edge loop unrolled x4 so
// four 512B row-gathers are in flight per wave.
__global__ __launch_bounds__(256) void agg_kernel(const float* __restrict__ tmp,
                                                  const int* __restrict__ row_ptr,
                                                  const int* __restrict__ csr_src,
                                                  const float* __restrict__ dinv,
                                                  const float* __restrict__ bias,
                                                  float* __restrict__ out, int n) {
    int wave = blockIdx.x * (blockDim.x >> 6) + (threadIdx.x >> 6);
    int lane = threadIdx.x & 63;
    if (wave >= n) return;
    int i = wave;

    float di = dinv[i];
    float2 self = ((const float2*)(tmp + (size_t)i * 128))[lane];
    float accx = self.x * di;
    float accy = self.y * di;

    int beg = row_ptr[i], end = row_ptr[i + 1];
    for (int e0 = beg; e0 < end; e0 += 64) {
        int m = end - e0; if (m > 64) m = 64;
        int   s  = 0;
        float cf = 0.f;
        if (lane < m) { s = csr_src[e0 + lane]; cf = dinv[s]; }
        int j = 0;
        for (; j + 4 <= m; j += 4) {
            int s0 = __shfl(s, j + 0), s1 = __shfl(s, j + 1);
            int s2 = __shfl(s, j + 2), s3 = __shfl(s, j + 3);
            float c0 = __shfl(cf, j + 0), c1 = __shfl(cf, j + 1);
            float c2 = __shfl(cf, j + 2), c3 = __shfl(cf, j + 3);
            float2 v0 = ((const float2*)(tmp + (size_t)s0 * 128))[lane];
            float2 v1 = ((const float2*)(tmp + (size_t)s1 * 128))[lane];
            float2 v2 = ((const float2*)(tmp + (size_t)s2 * 128))[lane];
            float2 v3 = ((const float2*)(tmp + (size_t)s3 * 128))[lane];
            accx += v0.x * c0; accy += v0.y * c0;
            accx += v1.x * c1; accy += v1.y * c1;
            accx += v2.x * c2; accy += v2.y * c2;
            accx += v3.x * c3; accy += v3.y * c3;
        }
        for (; j < m; j++) {
            int   sj = __shfl(s, j);
            float cj = __shfl(cf, j);
            float2 v = ((const float2*)(tmp + (size_t)sj * 128))[lane];
            accx += v.x * cj;
            accy += v.y * cj;
        }
    }
    float2 b = ((const float2*)bias)[lane];
    float2 o;
    o.x = fmaxf(fmaf(accx, di, b.x), 0.f);
    o.y = fmaxf(fmaf(accy, di, b.y), 0.f);
    ((float2*)(out + (size_t)i * 128))[lane] = o;
}

// ---- mean pool per graph + FC(128->1); fp64 accumulation ------------------
__global__ __launch_bounds__(128) void pool_fc_kernel(const float* __restrict__ h,
                                                      const int* __restrict__ batch,
                                                      const float* __restrict__ Wfc,
                                                      const float* __restrict__ bfc,
                                                      float* __restrict__ out, int n) {
    int g = blockIdx.x;
    int c = threadIdx.x;

    int lo = 0, hi = n;
    while (lo < hi) { int mid = (lo + hi) >> 1; if (batch[mid] < g) lo = mid + 1; else hi = mid; }
    int start = lo;
    lo = start; hi = n;
    while (lo < hi) { int mid = (lo + hi) >> 1; if (batch[mid] < g + 1) lo = mid + 1; else hi = mid; }
    int end = lo;

    double sum = 0.0;
    for (int r = start; r < end; r++) sum += (double)h[(size_t)r * 128 + c];
    int cnt = end - start;
    double mean = sum / (double)(cnt > 0 ? cnt : 1);
    double v = mean * (double)Wfc[c];

    __shared__ double red[128];
    red[c] = v;
    __syncthreads();
    for (int off = 64; off > 0; off >>= 1) {
        if (c < off) red[c] += red[c + off];
        __syncthreads();
    }
    if (c == 0) out[g] = (float)(red[0] + (double)bfc[0]);
}

// ---------------------------------------------------------------------------
extern "C" void kernel_launch(void* const* d_in, const int* in_sizes, int n_in,
                              void* d_out, int out_size, void* d_ws, size_t ws_size,
                              hipStream_t stream) {
    const float* x          = (const float*)d_in[0];
    const int*   edge_index = (const int*)d_in[1];
    const int*   batch      = (const int*)d_in[2];
    const float* W1  = (const float*)d_in[3];
    const float* b1  = (const float*)d_in[4];
    const float* W2  = (const float*)d_in[5];
    const float* b2  = (const float*)d_in[6];
    const float* Wfc = (const float*)d_in[7];
    const float* bfc = (const float*)d_in[8];
    float* out = (float*)d_out;

    const int N = in_sizes[2];       // 50000
    const int E = in_sizes[1] / 2;   // 1600000
    const int G = out_size;          // 128 graphs

    const int* e_src = edge_index;
    const int* e_dst = edge_index + E;

    char* p = (char*)d_ws;
    auto alloc = [&](size_t bytes) {
        void* r = (void*)p;
        p += (bytes + 255) & ~(size_t)255;
        return r;
    };
    float* h0       = (float*)alloc((size_t)N * 128 * 4);
    float* h1       = (float*)alloc((size_t)N * 128 * 4);
    int*   csr_src  = (int*)  alloc((size_t)E * 4);
    int*   row_ptr  = (int*)  alloc((size_t)(N + 1) * 4);
    int*   deg_cnt  = (int*)  alloc((size_t)N * 4);
    int*   fill     = (int*)  alloc((size_t)N * 4);
    float* dinv     = (float*)alloc((size_t)N * 4);
    (void)ws_size; (void)n_in;

    hipMemsetAsync(deg_cnt, 0, (size_t)N * 4, stream);
    hipMemsetAsync(fill,    0, (size_t)N * 4, stream);

    int tb = 256;
    int e4 = (E + 3) / 4;
    count_deg_kernel<<<(e4 + tb - 1) / tb, tb, 0, stream>>>(e_dst, deg_cnt, E);
    dinv_kernel<<<(N + tb - 1) / tb, tb, 0, stream>>>(deg_cnt, dinv, N);
    scan_kernel<<<1, 1024, 0, stream>>>(deg_cnt, row_ptr, N);
    csr_fill_kernel<<<1024, 256, 0, stream>>>(e_src, e_dst, row_ptr, fill, csr_src, E, N);

    int gemm_blocks = (N + 63) / 64;
    int agg_blocks  = (N + 3) / 4;

    gemm_kernel<<<gemm_blocks, 256, 0, stream>>>(x, W1, h1, N);
    agg_kernel<<<agg_blocks, 256, 0, stream>>>(h1, row_ptr, csr_src, dinv, b1, h0, N);

    for (int l = 0; l < 3; l++) {
        gemm_kernel<<<gemm_blocks, 256, 0, stream>>>(h0, W2, h1, N);
        agg_kernel<<<agg_blocks, 256, 0, stream>>>(h1, row_ptr, csr_src, dinv, b2, h0, N);
    }

    pool_fc_kernel<<<G, 128, 0, stream>>>(h0, batch, Wfc, bfc, out, N);
}

// Round 3
// 929.057 us; speedup vs baseline: 1.3877x; 1.2896x over previous
//
#include <hip/hip_runtime.h>
#include <hip/hip_bf16.h>

// ---------------------------------------------------------------------------
// GCNRegression: 4x (GEMM 128x128 + symmetric-norm aggregation + ReLU),
// then global mean pool (128 graphs) + FC(128->1).
//
// R2 notes:
//  - pool_fc was 114us: 1 wave/CU, serial dependent loads. -> two-stage pool
//    (1024 blocks partial sums + atomicAdd, then tiny FC kernel).
//  - gemm was 118us at VALUBusy 15.8%: 64KB LDS capped occupancy at 2
//    blocks/CU and no A-load lookahead. -> 32KB LDS (64-col W halves),
//    128-row tiles, explicit next-chunk A prefetch.
// ---------------------------------------------------------------------------

// ---- degree histogram (int4-vectorized edge reads) ------------------------
__global__ void count_deg_kernel(const int* __restrict__ dst, int* __restrict__ deg, int E) {
    int i = blockIdx.x * blockDim.x + threadIdx.x;
    int e = i * 4;
    if (e + 3 < E) {
        int4 d = *(const int4*)(dst + e);
        atomicAdd(&deg[d.x], 1);
        atomicAdd(&deg[d.y], 1);
        atomicAdd(&deg[d.z], 1);
        atomicAdd(&deg[d.w], 1);
    } else {
        for (; e < E; e++) atomicAdd(&deg[dst[e]], 1);
    }
}

// ---- dinv = 1/sqrt(deg+1) -------------------------------------------------
__global__ void dinv_kernel(const int* __restrict__ deg, float* __restrict__ dinv, int n) {
    int i = blockIdx.x * blockDim.x + threadIdx.x;
    if (i < n) dinv[i] = (float)(1.0 / sqrt((double)(deg[i] + 1)));
}

// ---- single-block exclusive scan -> row_ptr -------------------------------
__global__ void scan_kernel(const int* __restrict__ cnt, int* __restrict__ row_ptr, int n) {
    __shared__ int sums[1024];
    int t = threadIdx.x;
    int per = (n + 1023) >> 10;
    int s = t * per;
    int e = s + per; if (e > n) e = n; if (s > n) s = n;
    int acc = 0;
    for (int i = s; i < e; i++) acc += cnt[i];
    sums[t] = acc;
    __syncthreads();
    for (int off = 1; off < 1024; off <<= 1) {
        int u = (t >= off) ? sums[t - off] : 0;
        __syncthreads();
        sums[t] += u;
        __syncthreads();
    }
    int excl = sums[t] - acc;
    int run = excl;
    for (int i = s; i < e; i++) { row_ptr[i] = run; run += cnt[i]; }
    if (t == 1023) row_ptr[n] = sums[1023];
}

// ---- CSR fill, XCD-range-partitioned --------------------------------------
__global__ __launch_bounds__(256) void csr_fill_kernel(const int* __restrict__ src,
                                                       const int* __restrict__ dst,
                                                       const int* __restrict__ row_ptr,
                                                       int* __restrict__ fill,
                                                       int* __restrict__ csr_src,
                                                       int E, int N) {
    int g  = blockIdx.x & 7;
    int gb = blockIdx.x >> 3;
    int group_blocks = gridDim.x >> 3;
    int R  = (N + 7) >> 3;
    int lo = g * R;
    int hi = lo + R; if (hi > N) hi = N;

    int tig    = gb * blockDim.x + threadIdx.x;
    int stride = group_blocks * blockDim.x;
    int nq = (E + 3) >> 2;

    for (int q = tig; q < nq; q += stride) {
        int e = q * 4;
        if (e + 3 < E) {
            int4 d = *(const int4*)(dst + e);
            if (d.x >= lo && d.x < hi) {
                int pos = row_ptr[d.x] + atomicAdd(&fill[d.x], 1);
                csr_src[pos] = src[e + 0];
            }
            if (d.y >= lo && d.y < hi) {
                int pos = row_ptr[d.y] + atomicAdd(&fill[d.y], 1);
                csr_src[pos] = src[e + 1];
            }
            if (d.z >= lo && d.z < hi) {
                int pos = row_ptr[d.z] + atomicAdd(&fill[d.z], 1);
                csr_src[pos] = src[e + 2];
            }
            if (d.w >= lo && d.w < hi) {
                int pos = row_ptr[d.w] + atomicAdd(&fill[d.w], 1);
                csr_src[pos] = src[e + 3];
            }
        } else {
            for (; e < E; e++) {
                int d = dst[e];
                if (d >= lo && d < hi) {
                    int pos = row_ptr[d] + atomicAdd(&fill[d], 1);
                    csr_src[pos] = src[e];
                }
            }
        }
    }
}

// ---- GEMM: C[n x 128] = A[n x 128] @ W[128 x 128] -------------------------
// Grid = (row tiles of 128) x (2 col-halves of 64). W-half (128k x 64c) in
// 32KB LDS -> ~4 blocks/CU. Per thread: 8 rows x 4 cols, A prefetched one
// k-chunk ahead.
__global__ __launch_bounds__(256) void gemm_kernel(const float* __restrict__ A,
                                                   const float* __restrict__ W,
                                                   float* __restrict__ C, int n) {
    __shared__ float sW[128 * 64];
    int t = threadIdx.x;
    int col0 = (blockIdx.x & 1) * 64;
    int row0 = (blockIdx.x >> 1) * 128;

    // stage W half: 2048 float4, 8 per thread
    {
        #pragma unroll
        for (int i = 0; i < 8; i++) {
            int fidx = t + 256 * i;           // float4 index
            int k  = fidx >> 4;               // 16 float4 per k-row
            int c4 = fidx & 15;
            *(float4*)(sW + k * 64 + c4 * 4) =
                *(const float4*)(W + (size_t)k * 128 + col0 + c4 * 4);
        }
    }
    __syncthreads();

    int cg = (t & 15) * 4;          // 4 cols within half
    int rg = (t >> 4) * 8;          // 8 rows
    int rbase = row0 + rg;

    float acc[8][4];
    #pragma unroll
    for (int r = 0; r < 8; r++)
        #pragma unroll
        for (int c = 0; c < 4; c++) acc[r][c] = 0.f;

    float4 a_cur[8], a_nxt[8];
    #pragma unroll
    for (int r = 0; r < 8; r++) {
        int rr = rbase + r;
        a_cur[r] = (rr < n) ? *(const float4*)(A + (size_t)rr * 128)
                            : make_float4(0.f, 0.f, 0.f, 0.f);
    }

    for (int k = 0; k < 128; k += 4) {
        if (k + 4 < 128) {
            #pragma unroll
            for (int r = 0; r < 8; r++) {
                int rr = rbase + r;
                a_nxt[r] = (rr < n) ? *(const float4*)(A + (size_t)rr * 128 + k + 4)
                                    : make_float4(0.f, 0.f, 0.f, 0.f);
            }
        }
        #pragma unroll
        for (int kk = 0; kk < 4; kk++) {
            float4 w = *(const float4*)(sW + (size_t)(k + kk) * 64 + cg);
            #pragma unroll
            for (int r = 0; r < 8; r++) {
                float av = (kk == 0) ? a_cur[r].x : (kk == 1) ? a_cur[r].y
                         : (kk == 2) ? a_cur[r].z : a_cur[r].w;
                acc[r][0] = fmaf(av, w.x, acc[r][0]);
                acc[r][1] = fmaf(av, w.y, acc[r][1]);
                acc[r][2] = fmaf(av, w.z, acc[r][2]);
                acc[r][3] = fmaf(av, w.w, acc[r][3]);
            }
        }
        #pragma unroll
        for (int r = 0; r < 8; r++) a_cur[r] = a_nxt[r];
    }
    #pragma unroll
    for (int r = 0; r < 8; r++) {
        int rr = rbase + r;
        if (rr < n)
            *(float4*)(C + (size_t)rr * 128 + col0 + cg) =
                make_float4(acc[r][0], acc[r][1], acc[r][2], acc[r][3]);
    }
}

// ---- Aggregation ----------------------------------------------------------
__global__ __launch_bounds__(256) void agg_kernel(const float* __restrict__ tmp,
                                                  const int* __restrict__ row_ptr,
                                                  const int* __restrict__ csr_src,
                                                  const float* __restrict__ dinv,
                                                  const float* __restrict__ bias,
                                                  float* __restrict__ out, int n) {
    int wave = blockIdx.x * (blockDim.x >> 6) + (threadIdx.x >> 6);
    int lane = threadIdx.x & 63;
    if (wave >= n) return;
    int i = wave;

    float di = dinv[i];
    float2 self = ((const float2*)(tmp + (size_t)i * 128))[lane];
    float accx = self.x * di;
    float accy = self.y * di;

    int beg = row_ptr[i], end = row_ptr[i + 1];
    for (int e0 = beg; e0 < end; e0 += 64) {
        int m = end - e0; if (m > 64) m = 64;
        int   s  = 0;
        float cf = 0.f;
        if (lane < m) { s = csr_src[e0 + lane]; cf = dinv[s]; }
        int j = 0;
        for (; j + 4 <= m; j += 4) {
            int s0 = __shfl(s, j + 0), s1 = __shfl(s, j + 1);
            int s2 = __shfl(s, j + 2), s3 = __shfl(s, j + 3);
            float c0 = __shfl(cf, j + 0), c1 = __shfl(cf, j + 1);
            float c2 = __shfl(cf, j + 2), c3 = __shfl(cf, j + 3);
            float2 v0 = ((const float2*)(tmp + (size_t)s0 * 128))[lane];
            float2 v1 = ((const float2*)(tmp + (size_t)s1 * 128))[lane];
            float2 v2 = ((const float2*)(tmp + (size_t)s2 * 128))[lane];
            float2 v3 = ((const float2*)(tmp + (size_t)s3 * 128))[lane];
            accx += v0.x * c0; accy += v0.y * c0;
            accx += v1.x * c1; accy += v1.y * c1;
            accx += v2.x * c2; accy += v2.y * c2;
            accx += v3.x * c3; accy += v3.y * c3;
        }
        for (; j < m; j++) {
            int   sj = __shfl(s, j);
            float cj = __shfl(cf, j);
            float2 v = ((const float2*)(tmp + (size_t)sj * 128))[lane];
            accx += v.x * cj;
            accy += v.y * cj;
        }
    }
    float2 b = ((const float2*)bias)[lane];
    float2 o;
    o.x = fmaxf(fmaf(accx, di, b.x), 0.f);
    o.y = fmaxf(fmaf(accy, di, b.y), 0.f);
    ((float2*)(out + (size_t)i * 128))[lane] = o;
}

// ---- pool stage 1: partial sums per (graph, split) -> atomicAdd -----------
__global__ __launch_bounds__(128) void pool_partial_kernel(const float* __restrict__ h,
                                                           const int* __restrict__ batch,
                                                           float* __restrict__ sums,
                                                           int n, int S) {
    int g = blockIdx.x / S;
    int s = blockIdx.x % S;
    int c = threadIdx.x;

    int lo = 0, hi = n;
    while (lo < hi) { int mid = (lo + hi) >> 1; if (batch[mid] < g) lo = mid + 1; else hi = mid; }
    int start = lo;
    lo = start; hi = n;
    while (lo < hi) { int mid = (lo + hi) >> 1; if (batch[mid] < g + 1) lo = mid + 1; else hi = mid; }
    int end = lo;

    int cnt = end - start;
    int per = (cnt + S - 1) / S;
    int rs = start + s * per;
    int re = rs + per; if (re > end) re = end;
    if (rs >= re) return;

    float a0 = 0.f, a1 = 0.f, a2 = 0.f, a3 = 0.f;
    int r = rs;
    for (; r + 4 <= re; r += 4) {
        a0 += h[(size_t)(r + 0) * 128 + c];
        a1 += h[(size_t)(r + 1) * 128 + c];
        a2 += h[(size_t)(r + 2) * 128 + c];
        a3 += h[(size_t)(r + 3) * 128 + c];
    }
    for (; r < re; r++) a0 += h[(size_t)r * 128 + c];
    atomicAdd(&sums[g * 128 + c], (a0 + a1) + (a2 + a3));
}

// ---- pool stage 2: mean + FC(128->1), fp64 reduce -------------------------
__global__ __launch_bounds__(128) void pool_fc_final_kernel(const float* __restrict__ sums,
                                                            const int* __restrict__ batch,
                                                            const float* __restrict__ Wfc,
                                                            const float* __restrict__ bfc,
                                                            float* __restrict__ out, int n) {
    int g = blockIdx.x;
    int c = threadIdx.x;

    int lo = 0, hi = n;
    while (lo < hi) { int mid = (lo + hi) >> 1; if (batch[mid] < g) lo = mid + 1; else hi = mid; }
    int start = lo;
    lo = start; hi = n;
    while (lo < hi) { int mid = (lo + hi) >> 1; if (batch[mid] < g + 1) lo = mid + 1; else hi = mid; }
    int cnt = lo - start;

    double mean = (double)sums[g * 128 + c] / (double)(cnt > 0 ? cnt : 1);
    double v = mean * (double)Wfc[c];

    __shared__ double red[128];
    red[c] = v;
    __syncthreads();
    for (int off = 64; off > 0; off >>= 1) {
        if (c < off) red[c] += red[c + off];
        __syncthreads();
    }
    if (c == 0) out[g] = (float)(red[0] + (double)bfc[0]);
}

// ---------------------------------------------------------------------------
extern "C" void kernel_launch(void* const* d_in, const int* in_sizes, int n_in,
                              void* d_out, int out_size, void* d_ws, size_t ws_size,
                              hipStream_t stream) {
    const float* x          = (const float*)d_in[0];
    const int*   edge_index = (const int*)d_in[1];
    const int*   batch      = (const int*)d_in[2];
    const float* W1  = (const float*)d_in[3];
    const float* b1  = (const float*)d_in[4];
    const float* W2  = (const float*)d_in[5];
    const float* b2  = (const float*)d_in[6];
    const float* Wfc = (const float*)d_in[7];
    const float* bfc = (const float*)d_in[8];
    float* out = (float*)d_out;

    const int N = in_sizes[2];       // 50000
    const int E = in_sizes[1] / 2;   // 1600000
    const int G = out_size;          // 128 graphs

    const int* e_src = edge_index;
    const int* e_dst = edge_index + E;

    char* p = (char*)d_ws;
    auto alloc = [&](size_t bytes) {
        void* r = (void*)p;
        p += (bytes + 255) & ~(size_t)255;
        return r;
    };
    float* h0        = (float*)alloc((size_t)N * 128 * 4);
    float* h1        = (float*)alloc((size_t)N * 128 * 4);
    int*   csr_src   = (int*)  alloc((size_t)E * 4);
    int*   row_ptr   = (int*)  alloc((size_t)(N + 1) * 4);
    int*   deg_cnt   = (int*)  alloc((size_t)N * 4);
    int*   fill      = (int*)  alloc((size_t)N * 4);
    float* dinv      = (float*)alloc((size_t)N * 4);
    float* pool_sums = (float*)alloc((size_t)G * 128 * 4);
    (void)ws_size; (void)n_in;

    hipMemsetAsync(deg_cnt,   0, (size_t)N * 4, stream);
    hipMemsetAsync(fill,      0, (size_t)N * 4, stream);
    hipMemsetAsync(pool_sums, 0, (size_t)G * 128 * 4, stream);

    int tb = 256;
    int e4 = (E + 3) / 4;
    count_deg_kernel<<<(e4 + tb - 1) / tb, tb, 0, stream>>>(e_dst, deg_cnt, E);
    dinv_kernel<<<(N + tb - 1) / tb, tb, 0, stream>>>(deg_cnt, dinv, N);
    scan_kernel<<<1, 1024, 0, stream>>>(deg_cnt, row_ptr, N);
    csr_fill_kernel<<<1024, 256, 0, stream>>>(e_src, e_dst, row_ptr, fill, csr_src, E, N);

    int gemm_blocks = 2 * ((N + 127) / 128);
    int agg_blocks  = (N + 3) / 4;

    gemm_kernel<<<gemm_blocks, 256, 0, stream>>>(x, W1, h1, N);
    agg_kernel<<<agg_blocks, 256, 0, stream>>>(h1, row_ptr, csr_src, dinv, b1, h0, N);

    for (int l = 0; l < 3; l++) {
        gemm_kernel<<<gemm_blocks, 256, 0, stream>>>(h0, W2, h1, N);
        agg_kernel<<<agg_blocks, 256, 0, stream>>>(h1, row_ptr, csr_src, dinv, b2, h0, N);
    }

    const int S = 8;
    pool_partial_kernel<<<G * S, 128, 0, stream>>>(h0, batch, pool_sums, N, S);
    pool_fc_final_kernel<<<G, 128, 0, stream>>>(pool_sums, batch, Wfc, bfc, out, N);
}